// Round 12
// baseline (496.538 us; speedup 1.0000x reference)
//
#include <hip/hip_runtime.h>
#include <math.h>

// VQVAE forward — R18 (resubmit; R11 bench = GPUAcquisitionTimeout, no
// data). 8-wave (512-thread) blocks, 16 rows/wave, 128 rows/block.
// R17 post-mortem: 64-row blocks halved compute/block but kept
// staging/block constant -> total staging traffic 2x, MfmaUtil 35->22,
// mega 398us. R17 DID prove the 16-row wave allocates 68 arch VGPR + 32
// AGPR (~100 unified, no spill) under a (.,3) cap. R18 combines the proven
// pieces: R12's 128-rows/block staging amortization + R17's halved wave
// footprint -> 2 blocks/CU x 8 waves = 4 waves/SIMD (up from 3, the wall
// since R12). LDS 32768 B: staging LP[0..8191] (A: W2 8192 halves hi+lo;
// C: CB 8192; E: WD2 8192; reused sequentially, barrier-protected) + WPS
// 8 x 1024 halves. Z-transpose in per-wave WPS as TWO sequential passes
// (hi then lo, same 1024-half region; same-wave in-order LDS + compiler
// same-address dependence make read-then-overwrite safe). Staging indices
// rescaled for 512 threads (2 half8/thread for A/C/E; audited R11 wait:
// slot unions bijective, read XOR matches write XOR per row). esp =
// blockIdx*8+w (16384 partials, finalize sums 16).
// Numerics identical to R16/R17 (harness-validated): fp16 split-2 enc+VQ,
// cnv folded into accd init, plain fp16 dec.

namespace {

constexpr int kN = 262144;

typedef _Float16 half8 __attribute__((ext_vector_type(8)));
typedef float floatx4 __attribute__((ext_vector_type(4)));

#define MFMA16(a, b, c) __builtin_amdgcn_mfma_f32_16x16x32_f16((a), (b), (c), 0, 0, 0)
#define LDS_FENCE() asm volatile("s_waitcnt lgkmcnt(0)" ::: "memory")
#define VMCNT0() asm volatile("s_waitcnt vmcnt(0)" ::: "memory")
#define BARRIER()                                  \
  do {                                             \
    asm volatile("" ::: "memory");                 \
    __builtin_amdgcn_s_barrier();                  \
    asm volatile("" ::: "memory");                 \
  } while (0)

// ---- workspace byte offsets (weights region, as R4-R17)
constexpr size_t W1M_O = 0;        // ew1 padded [256][32] f16 (k>=9 zero), main
constexpr size_t W1R_O = 16384;    // residual
constexpr size_t E2M_O = 32768;    // ew2 [128][256]
constexpr size_t E2R_O = 98304;
constexpr size_t E3M_O = 163840;   // ew3 [64][128]
constexpr size_t E3R_O = 180224;
constexpr size_t CBM_O = 196608;   // codebook [1024][64]
constexpr size_t CBR_O = 327680;
constexpr size_t D1P_O = 458752;   // dw1 [128][64] plain
constexpr size_t D2P_O = 475136;   // dw2 [256][128] plain
constexpr size_t D3P_O = 540672;   // dw3 padded [16][256] plain
constexpr size_t CN_O  = 548864;   // cn [1024] f32
// ---- small outputs (grid 2048 x 8 waves -> esp 16384 floats)
constexpr size_t IDX_O = 589824;             // idx [N] i32 (1 MB)
constexpr size_t ESP_O = IDX_O + 1048576;    // es partials [16384] f32 (64 KB)
constexpr size_t HP_O  = ESP_O + 65536;      // hist partials [64][1024] i32

__device__ __forceinline__ void split2(float v, _Float16& hi, _Float16& lo) {
  hi = (_Float16)v;
  lo = (_Float16)(v - (float)hi);
}

// =====================================================================
__global__ void prep_kernel(
    const float* __restrict__ ew1, const float* __restrict__ ew2,
    const float* __restrict__ ew3, const float* __restrict__ cb,
    const float* __restrict__ dw1, const float* __restrict__ dw2,
    const float* __restrict__ dw3, char* __restrict__ wsb) {
  _Float16* w1m = (_Float16*)(wsb + W1M_O);
  _Float16* w1r = (_Float16*)(wsb + W1R_O);
  _Float16* e2m = (_Float16*)(wsb + E2M_O);
  _Float16* e2r = (_Float16*)(wsb + E2R_O);
  _Float16* e3m = (_Float16*)(wsb + E3M_O);
  _Float16* e3r = (_Float16*)(wsb + E3R_O);
  _Float16* cbm = (_Float16*)(wsb + CBM_O);
  _Float16* cbr = (_Float16*)(wsb + CBR_O);
  _Float16* d1p = (_Float16*)(wsb + D1P_O);
  _Float16* d2p = (_Float16*)(wsb + D2P_O);
  _Float16* d3p = (_Float16*)(wsb + D3P_O);
  float* cn = (float*)(wsb + CN_O);

  const int gid = blockIdx.x * 256 + threadIdx.x;
  const int stride = gridDim.x * 256;
  for (int e = gid; e < 256 * 32; e += stride) {
    int n = e >> 5, k = e & 31;
    float v = (k < 9) ? ew1[n * 9 + k] : 0.f;
    split2(v, w1m[e], w1r[e]);
  }
  for (int e = gid; e < 128 * 256; e += stride) split2(ew2[e], e2m[e], e2r[e]);
  for (int e = gid; e < 64 * 128; e += stride) split2(ew3[e], e3m[e], e3r[e]);
  for (int e = gid; e < 1024 * 64; e += stride) split2(cb[e], cbm[e], cbr[e]);
  for (int e = gid; e < 128 * 64; e += stride) d1p[e] = (_Float16)dw1[e];
  for (int e = gid; e < 256 * 128; e += stride) d2p[e] = (_Float16)dw2[e];
  for (int e = gid; e < 16 * 256; e += stride) {
    int n = e >> 8, k = e & 255;
    d3p[e] = (n < 9) ? (_Float16)dw3[n * 256 + k] : (_Float16)0.f;
  }
  for (int i = gid; i < 1024; i += stride) {
    float s = 0.f;
    const float* c = cb + (size_t)i * 64;
#pragma unroll 8
    for (int k = 0; k < 64; ++k) s = fmaf(c[k], c[k], s);
    cn[i] = s;
  }
}

// =====================================================================
// Megakernel: 128 rows/block, 8 waves x 16 rows, grid 2048.
__global__ __launch_bounds__(512, 3) void vqvae_mega(
    const float* __restrict__ x,
    const float* __restrict__ eb1, const float* __restrict__ eb2,
    const float* __restrict__ eb3, const float* __restrict__ db1,
    const float* __restrict__ db2, const float* __restrict__ db3,
    const float* __restrict__ cb, const char* __restrict__ wsb,
    float* __restrict__ out, int* __restrict__ idx_g, float* __restrict__ esp_g) {
  __shared__ _Float16 LP[16384];  // 32768 B: [0..8191] staging, [8192..] WPS

  const int t = threadIdx.x;
  const int lane = t & 63;
  const int w = t >> 6;
  const int m = lane & 15;
  const int q = lane >> 4;
  const int R0 = blockIdx.x * 128;
  const int row0 = R0 + w * 16;
  _Float16* WPS = LP + 8192 + w * 1024;
  const float* cn_g = (const float*)(wsb + CN_O);

  const int mh = m >> 3, ml = m & 7, m3 = m & 3, m7 = m & 7;
  const int rA = m * 32 + ((q ^ m3) << 3);  // 32-col tile read (row m, grp q)
  const int z0 = m * 64 + ((q ^ m7) << 3);        // 64-col tile, K-grp q
  const int z1 = m * 64 + (((4 + q) ^ m7) << 3);  // 64-col tile, K-grp 4+q

  half8 axm = {}, axr = {};
  {
    const int grow = row0 + m;
    if (q == 0) {
#pragma unroll
      for (int j = 0; j < 8; ++j) {
        const float v = x[(size_t)grow * 9 + j];
        const _Float16 hi = (_Float16)v;
        axm[j] = hi;
        axr[j] = (_Float16)(v - (float)hi);
      }
    } else if (q == 1) {
      const float v = x[(size_t)grow * 9 + 8];
      const _Float16 hi = (_Float16)v;
      axm[0] = hi;
      axr[0] = (_Float16)(v - (float)hi);
    }
  }

  // ================= Stage A: enc1 fused with enc2 (staged W2, T14)
  floatx4 acc2[8];
#pragma unroll
  for (int nt = 0; nt < 8; ++nt) acc2[nt] = (floatx4){0.f, 0.f, 0.f, 0.f};

  {
    // 512-thread staging: 256 threads/buffer, 2 half8 each (half a row)
    const int pA = t >> 8, eA = t & 255;
    const int nA = eA >> 1, hA = eA & 1;
    const char* srcA = wsb + (pA ? E2R_O : E2M_O) + (size_t)nA * 512 + hA * 32;
    _Float16* dstA = LP + pA * 4096 + nA * 32;
    const int sA = nA & 3;
    const int jA0 = hA * 2, jA1 = hA * 2 + 1;
    half8 stg0 = *(const half8*)(srcA);
    half8 stg1 = *(const half8*)(srcA + 16);

    for (int kc = 0; kc < 8; ++kc) {
      VMCNT0();
      *(half8*)(dstA + ((jA0 ^ sA) << 3)) = stg0;
      *(half8*)(dstA + ((jA1 ^ sA) << 3)) = stg1;
      LDS_FENCE();
      if (kc < 7) {
        stg0 = *(const half8*)(srcA + (size_t)(kc + 1) * 64);
        stg1 = *(const half8*)(srcA + (size_t)(kc + 1) * 64 + 16);
      }
      BARRIER();

#pragma unroll
      for (int ntl = 0; ntl < 2; ++ntl) {
        const int f = kc * 32 + ntl * 16 + m;
        const half8 bm = *(const half8*)(wsb + W1M_O + (size_t)f * 64 + q * 16);
        const half8 br = *(const half8*)(wsb + W1R_O + (size_t)f * 64 + q * 16);
        const float bias = eb1[f];
        floatx4 a = (floatx4){0.f, 0.f, 0.f, 0.f};
        a = MFMA16(axr, bm, a);
        a = MFMA16(axm, br, a);
        a = MFMA16(axm, bm, a);
#pragma unroll
        for (int reg = 0; reg < 4; ++reg) {
          const float v = fmaxf(a[reg] + bias, 0.f);
          const int r = 4 * q + reg;
          const int g = (ntl * 2 + mh) ^ reg;  // r&3 == reg
          const _Float16 hi = (_Float16)v;
          WPS[r * 32 + (g << 3) + ml] = hi;
          WPS[512 + r * 32 + (g << 3) + ml] = (_Float16)(v - (float)hi);
        }
      }
      LDS_FENCE();
      const half8 am = *(const half8*)(WPS + rA);
      const half8 ar = *(const half8*)(WPS + 512 + rA);
      __builtin_amdgcn_s_setprio(1);
#pragma unroll
      for (int nt = 0; nt < 8; ++nt) {
        const half8 bm = *(const half8*)(LP + nt * 512 + rA);
        const half8 br = *(const half8*)(LP + 4096 + nt * 512 + rA);
        acc2[nt] = MFMA16(ar, bm, acc2[nt]);
        acc2[nt] = MFMA16(am, br, acc2[nt]);
        acc2[nt] = MFMA16(am, bm, acc2[nt]);
      }
      __builtin_amdgcn_s_setprio(0);
      BARRIER();  // staged reads done -> next chunk may overwrite
    }
  }

  // ================= Stage B: enc3 (B direct from L2; H2 via WPS)
  floatx4 acc3[4];
#pragma unroll
  for (int nt = 0; nt < 4; ++nt) acc3[nt] = (floatx4){0.f, 0.f, 0.f, 0.f};

  for (int ks = 0; ks < 4; ++ks) {
#pragma unroll
    for (int h = 0; h < 2; ++h) {
      const int nt = 2 * ks + h;
      const float bias = eb2[nt * 16 + m];
#pragma unroll
      for (int reg = 0; reg < 4; ++reg) {
        const float v = fmaxf(acc2[nt][reg] + bias, 0.f);
        const int r = 4 * q + reg;
        const int g = (h * 2 + mh) ^ reg;
        const _Float16 hi = (_Float16)v;
        WPS[r * 32 + (g << 3) + ml] = hi;
        WPS[512 + r * 32 + (g << 3) + ml] = (_Float16)(v - (float)hi);
      }
    }
    LDS_FENCE();
    const half8 am = *(const half8*)(WPS + rA);
    const half8 ar = *(const half8*)(WPS + 512 + rA);
#pragma unroll
    for (int nt = 0; nt < 4; ++nt) {
      const half8 bm = *(const half8*)(wsb + E3M_O + (size_t)(nt * 16 + m) * 256 + ks * 64 + q * 16);
      const half8 br = *(const half8*)(wsb + E3R_O + (size_t)(nt * 16 + m) * 256 + ks * 64 + q * 16);
      acc3[nt] = MFMA16(ar, bm, acc3[nt]);
      acc3[nt] = MFMA16(am, br, acc3[nt]);
      acc3[nt] = MFMA16(am, bm, acc3[nt]);
    }
  }

  // ---- Stage C prologue: issue chunk-0 codebook loads (hide under Z)
  const int pC = t >> 8, eC = t & 255;
  const int nC = eC >> 2, hC = eC & 3;
  const char* srcC = wsb + (pC ? CBR_O : CBM_O) + (size_t)nC * 128 + hC * 32;
  _Float16* dstC = LP + pC * 4096 + nC * 64;
  const int sC = nC & 7;
  const int jC0 = hC * 2, jC1 = hC * 2 + 1;
  half8 stgC0 = *(const half8*)(srcC);
  half8 stgC1 = *(const half8*)(srcC + 16);

  // ---- Z epilogue -> register fragments, via per-wave WPS in TWO passes
  // (hi then lo, same 1024-half region; same-wave in-order LDS).
  half8 zfm[2], zfr[2];
#pragma unroll
  for (int nt = 0; nt < 4; ++nt) {
    const float bias = eb3[nt * 16 + m];
#pragma unroll
    for (int reg = 0; reg < 4; ++reg) {
      const float v = acc3[nt][reg] + bias;
      const int r = 4 * q + reg;
      const int g = (nt * 2 + mh) ^ (r & 7);
      WPS[r * 64 + (g << 3) + ml] = (_Float16)v;
    }
  }
  LDS_FENCE();
  zfm[0] = *(const half8*)(WPS + z0);
  zfm[1] = *(const half8*)(WPS + z1);
#pragma unroll
  for (int nt = 0; nt < 4; ++nt) {
    const float bias = eb3[nt * 16 + m];
#pragma unroll
    for (int reg = 0; reg < 4; ++reg) {
      const float v = acc3[nt][reg] + bias;
      const _Float16 hi = (_Float16)v;
      const int r = 4 * q + reg;
      const int g = (nt * 2 + mh) ^ (r & 7);
      WPS[r * 64 + (g << 3) + ml] = (_Float16)(v - (float)hi);
    }
  }
  LDS_FENCE();
  zfr[0] = *(const half8*)(WPS + z0);
  zfr[1] = *(const half8*)(WPS + z1);

  // ================= Stage C: VQ argmax-score (staged CB, cnv folded)
  // Staging region free: stage A's final barrier drained all W2 reads;
  // stage B/Z touch only WPS + L2.
  float bests[4];
  int besti[4];
#pragma unroll
  for (int reg = 0; reg < 4; ++reg) { bests[reg] = -3.4e38f; besti[reg] = 0; }

  for (int cc = 0; cc < 16; ++cc) {
    VMCNT0();
    *(half8*)(dstC + ((jC0 ^ sC) << 3)) = stgC0;
    *(half8*)(dstC + ((jC1 ^ sC) << 3)) = stgC1;
    LDS_FENCE();
    if (cc < 15) {
      stgC0 = *(const half8*)(srcC + (size_t)(cc + 1) * 8192);
      stgC1 = *(const half8*)(srcC + (size_t)(cc + 1) * 8192 + 16);
    }
    BARRIER();

    floatx4 accd[4];
#pragma unroll
    for (int nt = 0; nt < 4; ++nt) {
      const float ci = -0.5f * cn_g[cc * 64 + nt * 16 + m];
      accd[nt] = (floatx4){ci, ci, ci, ci};
    }
    __builtin_amdgcn_s_setprio(1);
#pragma unroll
    for (int nt = 0; nt < 4; ++nt) {
      const half8 bm0 = *(const half8*)(LP + nt * 1024 + z0);
      const half8 br0 = *(const half8*)(LP + 4096 + nt * 1024 + z0);
      accd[nt] = MFMA16(zfr[0], bm0, accd[nt]);
      accd[nt] = MFMA16(zfm[0], br0, accd[nt]);
      accd[nt] = MFMA16(zfm[0], bm0, accd[nt]);
      const half8 bm1 = *(const half8*)(LP + nt * 1024 + z1);
      const half8 br1 = *(const half8*)(LP + 4096 + nt * 1024 + z1);
      accd[nt] = MFMA16(zfr[1], bm1, accd[nt]);
      accd[nt] = MFMA16(zfm[1], br1, accd[nt]);
      accd[nt] = MFMA16(zfm[1], bm1, accd[nt]);
    }
    __builtin_amdgcn_s_setprio(0);
#pragma unroll
    for (int nt = 0; nt < 4; ++nt) {
      const int code = cc * 64 + nt * 16 + m;
#pragma unroll
      for (int reg = 0; reg < 4; ++reg) {
        const float s = accd[nt][reg];  // score = dot - 0.5||c||^2 (maximize)
        if (s > bests[reg]) { bests[reg] = s; besti[reg] = code; }
      }
    }
    BARRIER();  // staged reads done -> next chunk may overwrite
  }
#pragma unroll
  for (int reg = 0; reg < 4; ++reg) {
#pragma unroll
    for (int off = 1; off < 16; off <<= 1) {
      const float os = __shfl_xor(bests[reg], off, 16);
      const int oi = __shfl_xor(besti[reg], off, 16);
      if (os > bests[reg] || (os == bests[reg] && oi < besti[reg])) {
        bests[reg] = os; besti[reg] = oi;
      }
    }
  }
  if (m == 0) {
#pragma unroll
    for (int reg = 0; reg < 4; ++reg)
      idx_g[row0 + 4 * q + reg] = besti[reg];  // plain store; hist follows
  }

  // ---- z_q + per-wave e_latent partial. After the width-16 butterfly all
  // lanes in a q-group hold that group's argmin. Row m -> group m>>2, reg m&3.
  const int sl = ((m >> 2) << 4) | m;
  half8 zq[2];
  float es = 0.f;
  {
    const int b0 = __shfl(besti[0], sl);
    const int b1 = __shfl(besti[1], sl);
    const int b2 = __shfl(besti[2], sl);
    const int b3v = __shfl(besti[3], sl);
    const int r2 = m & 3;
    const int bi = (r2 == 0) ? b0 : (r2 == 1) ? b1 : (r2 == 2) ? b2 : b3v;
#pragma unroll
    for (int ks2 = 0; ks2 < 2; ++ks2) {
      const float* cp = cb + (size_t)bi * 64 + ks2 * 32 + q * 8;
      const float4 c0 = *(const float4*)cp;
      const float4 c1 = *(const float4*)(cp + 4);
      float cv[8] = {c0.x, c0.y, c0.z, c0.w, c1.x, c1.y, c1.z, c1.w};
#pragma unroll
      for (int j = 0; j < 8; ++j) {
        const float z = (float)zfm[ks2][j] + (float)zfr[ks2][j];
        const float d = cv[j] - z;
        es = fmaf(d, d, es);
        zq[ks2][j] = (_Float16)(z + d);
      }
    }
  }
#pragma unroll
  for (int off = 1; off < 64; off <<= 1) es += __shfl_xor(es, off, 64);
  if (lane == 0) esp_g[blockIdx.x * 8 + w] = es;  // no atomic

  // ---- Stage E prologue: issue chunk-0 WD2 loads (hide under stage D)
  const int nE = t >> 3, jE = t & 7;
  const char* srcE = wsb + D2P_O + (size_t)nE * 256 + jE * 32;
  _Float16* dstE = LP + nE * 128;
  const int sE = nE & 15;
  const int jE0 = jE * 2, jE1 = jE * 2 + 1;
  half8 stgE0 = *(const half8*)(srcE);
  half8 stgE1 = *(const half8*)(srcE + 16);

  // ================= Stage D: dec1 (plain fp16, B direct)
  floatx4 accH[8];
#pragma unroll
  for (int nt = 0; nt < 8; ++nt) accH[nt] = (floatx4){0.f, 0.f, 0.f, 0.f};
  __builtin_amdgcn_s_setprio(1);
#pragma unroll
  for (int nt = 0; nt < 8; ++nt) {
#pragma unroll
    for (int ks2 = 0; ks2 < 2; ++ks2) {
      const half8 b = *(const half8*)(wsb + D1P_O + (size_t)(nt * 16 + m) * 128 + ks2 * 64 + q * 16);
      accH[nt] = MFMA16(zq[ks2], b, accH[nt]);
    }
  }
  __builtin_amdgcn_s_setprio(0);
  half8 h3f[4];
  for (int ks = 0; ks < 4; ++ks) {
#pragma unroll
    for (int h = 0; h < 2; ++h) {
      const int nt = 2 * ks + h;
      const float bias = db1[nt * 16 + m];
#pragma unroll
      for (int reg = 0; reg < 4; ++reg) {
        const float v = fmaxf(accH[nt][reg] + bias, 0.f);
        const int r = 4 * q + reg;
        const int g = (h * 2 + mh) ^ reg;
        WPS[r * 32 + (g << 3) + ml] = (_Float16)v;
      }
    }
    LDS_FENCE();
    h3f[ks] = *(const half8*)(WPS + rA);
  }

  // ================= Stage E: dec2 (staged WD2) fused with dec3
  // Staging region free: stage C's final barrier drained all CB reads.
  floatx4 accO = (floatx4){0.f, 0.f, 0.f, 0.f};
  for (int jc = 0; jc < 4; ++jc) {
    VMCNT0();
    *(half8*)(dstE + ((jE0 ^ sE) << 3)) = stgE0;
    *(half8*)(dstE + ((jE1 ^ sE) << 3)) = stgE1;
    LDS_FENCE();
    if (jc < 3) {
      stgE0 = *(const half8*)(srcE + (size_t)(jc + 1) * 16384);
      stgE1 = *(const half8*)(srcE + (size_t)(jc + 1) * 16384 + 16);
    }
    BARRIER();

    floatx4 accD2[4];
#pragma unroll
    for (int nt = 0; nt < 4; ++nt) accD2[nt] = (floatx4){0.f, 0.f, 0.f, 0.f};
    __builtin_amdgcn_s_setprio(1);
#pragma unroll
    for (int nt = 0; nt < 4; ++nt) {
      const int n2 = nt * 16 + m;
#pragma unroll
      for (int ks = 0; ks < 4; ++ks) {
        const half8 b = *(const half8*)(LP + n2 * 128 + (((ks * 4 + q) ^ m) << 3));
        accD2[nt] = MFMA16(h3f[ks], b, accD2[nt]);
      }
    }
    __builtin_amdgcn_s_setprio(0);
    half8 b3[2];
#pragma unroll
    for (int ks2 = 0; ks2 < 2; ++ks2)
      b3[ks2] = *(const half8*)(wsb + D3P_O + (size_t)m * 512 + jc * 128 + ks2 * 64 + q * 16);
#pragma unroll
    for (int nt = 0; nt < 4; ++nt) {
      const float bias = db2[jc * 64 + nt * 16 + m];
#pragma unroll
      for (int reg = 0; reg < 4; ++reg) {
        const float v = fmaxf(accD2[nt][reg] + bias, 0.f);
        const int r = 4 * q + reg;
        const int g = (nt * 2 + mh) ^ (r & 7);
        WPS[r * 64 + (g << 3) + ml] = (_Float16)v;
      }
    }
    LDS_FENCE();
    {
      const half8 a0 = *(const half8*)(WPS + z0);
      accO = MFMA16(a0, b3[0], accO);
      const half8 a1 = *(const half8*)(WPS + z1);
      accO = MFMA16(a1, b3[1], accO);
    }
    BARRIER();  // staged reads done -> next chunk may overwrite
  }
  if (m < 9) {
    const float bias = db3[m];
#pragma unroll
    for (int reg = 0; reg < 4; ++reg) {
      const size_t r = (size_t)(row0 + 4 * q + reg);
      out[r * 9 + m] = accO[reg] + bias;
    }
  }
}

// =====================================================================
__global__ __launch_bounds__(256) void hist_kernel(
    const int* __restrict__ idx_g, int* __restrict__ hp) {
  __shared__ int lh[1024];
  const int t = threadIdx.x;
#pragma unroll
  for (int i = 0; i < 4; ++i) lh[t * 4 + i] = 0;
  __syncthreads();
  for (int i = t; i < 4096; i += 256)
    atomicAdd(&lh[idx_g[blockIdx.x * 4096 + i]], 1);  // LDS atomic only
  __syncthreads();
  int* part = hp + blockIdx.x * 1024;
#pragma unroll
  for (int i = 0; i < 4; ++i) part[t * 4 + i] = lh[t * 4 + i];
}

// =====================================================================
__global__ __launch_bounds__(1024) void finalize_kernel(
    const int* __restrict__ hp, const float* __restrict__ esp,
    float* __restrict__ out2) {
  __shared__ double red[1024];
  __shared__ float rede[1024];
  const int t = threadIdx.x;
  int h = 0;
#pragma unroll 8
  for (int p = 0; p < 64; ++p) h += hp[p * 1024 + t];
  const float pr = (float)h * (1.0f / (float)kN);
  red[t] = (double)(pr * logf(pr + 1e-10f));
  float es = 0.f;
#pragma unroll
  for (int i = 0; i < 16; ++i) es += esp[i * 1024 + t];
  rede[t] = es;
  __syncthreads();
  for (int s = 512; s > 0; s >>= 1) {
    if (t < s) { red[t] += red[t + s]; rede[t] += rede[t + s]; }
    __syncthreads();
  }
  if (t == 0) {
    out2[0] = 1.25f * (rede[0] * (1.0f / ((float)kN * 64.0f)));
    out2[1] = expf((float)(-red[0]));
  }
}

}  // namespace

extern "C" void kernel_launch(void* const* d_in, const int* in_sizes, int n_in,
                              void* d_out, int out_size, void* d_ws, size_t ws_size,
                              hipStream_t stream) {
  const float* x   = (const float*)d_in[0];
  const float* ew1 = (const float*)d_in[1];
  const float* eb1 = (const float*)d_in[2];
  const float* ew2 = (const float*)d_in[3];
  const float* eb2 = (const float*)d_in[4];
  const float* ew3 = (const float*)d_in[5];
  const float* eb3 = (const float*)d_in[6];
  const float* dw1 = (const float*)d_in[7];
  const float* db1 = (const float*)d_in[8];
  const float* dw2 = (const float*)d_in[9];
  const float* db2 = (const float*)d_in[10];
  const float* dw3 = (const float*)d_in[11];
  const float* db3 = (const float*)d_in[12];
  const float* cb  = (const float*)d_in[13];
  float* out = (float*)d_out;
  char* wsb = (char*)d_ws;

  int* idx_g = (int*)(wsb + IDX_O);
  float* esp = (float*)(wsb + ESP_O);
  int* hp = (int*)(wsb + HP_O);

  prep_kernel<<<128, 256, 0, stream>>>(ew1, ew2, ew3, cb, dw1, dw2, dw3, wsb);
  vqvae_mega<<<kN / 128, 512, 0, stream>>>(x, eb1, eb2, eb3, db1, db2, db3, cb,
                                           wsb, out, idx_g, esp);
  hist_kernel<<<64, 256, 0, stream>>>(idx_g, hp);
  finalize_kernel<<<1, 1024, 0, stream>>>(hp, esp, out + (size_t)kN * 9);
}

// Round 13
// 322.394 us; speedup vs baseline: 1.5402x; 1.5402x over previous
//
#include <hip/hip_runtime.h>
#include <math.h>

// VQVAE forward — R19: revert to R14 (best measured: mega 260.5us, total
// 322.0us) + cnv-fold in stage C (the only validated strictly-positive
// micro-win from R16-R18). Occupancy program CLOSED: R16 (64-row blocks)
// broke staging amortization (MfmaUtil 22), R17's bound fix still lost
// (398us), R18 (8-wave 512-thread blocks, no spill, 68 VGPR) got LESS
// residency (Occupancy 23.5%, mega 448us) — the naive floor(512/regs)
// model does not predict residency for these shapes. Empirical optimum =
// 32 rows/wave x 4 waves x 256 threads, 3 waves/SIMD (R12-R15 family).
// A/B evidence on R14's remaining ~29% issue-idle: NOT barriers (R15
// -36% -> 0), NOT conflicts (R15 -46% -> 0), NOT staging latency (T14
// +5% only), NOT TLP (R16-R18 regress). Intra-wave dependent chain;
// remaining levers are high-risk relayouts with ~3% modeled upside.
// cnv-fold: accd[nt][rt] initialized with -0.5*||c||^2 -> score =
// dot - 0.5||c||^2, argmax score == argmin dist. Saves the fma in the
// 128-elem/chunk scan. Validated: R16/R17/R18 all passed with identical
// absmax under this exact fold (rounding shift ~1e-6 << 1e-4 scheme
// error << O(1) code gaps). Everything else bit-identical to R14.

namespace {

constexpr int kN = 262144;

typedef _Float16 half8 __attribute__((ext_vector_type(8)));
typedef float floatx4 __attribute__((ext_vector_type(4)));

#define MFMA16(a, b, c) __builtin_amdgcn_mfma_f32_16x16x32_f16((a), (b), (c), 0, 0, 0)
#define LDS_FENCE() asm volatile("s_waitcnt lgkmcnt(0)" ::: "memory")
#define VMCNT0() asm volatile("s_waitcnt vmcnt(0)" ::: "memory")
#define BARRIER()                                  \
  do {                                             \
    asm volatile("" ::: "memory");                 \
    __builtin_amdgcn_s_barrier();                  \
    asm volatile("" ::: "memory");                 \
  } while (0)

// ---- workspace byte offsets (weights region, as R4-R18)
constexpr size_t W1M_O = 0;        // ew1 padded [256][32] f16 (k>=9 zero), main
constexpr size_t W1R_O = 16384;    // residual
constexpr size_t E2M_O = 32768;    // ew2 [128][256]
constexpr size_t E2R_O = 98304;
constexpr size_t E3M_O = 163840;   // ew3 [64][128]
constexpr size_t E3R_O = 180224;
constexpr size_t CBM_O = 196608;   // codebook [1024][64]
constexpr size_t CBR_O = 327680;
constexpr size_t D1P_O = 458752;   // dw1 [128][64] plain
constexpr size_t D2P_O = 475136;   // dw2 [256][128] plain
constexpr size_t D3P_O = 540672;   // dw3 padded [16][256] plain
constexpr size_t CN_O  = 548864;   // cn [1024] f32
// ---- small outputs
constexpr size_t IDX_O = 589824;             // idx [N] i32 (1 MB)
constexpr size_t ESP_O = IDX_O + 1048576;    // es partials [8192] f32
constexpr size_t HP_O  = ESP_O + 32768;      // hist partials [64][1024] i32

__device__ __forceinline__ void split2(float v, _Float16& hi, _Float16& lo) {
  hi = (_Float16)v;
  lo = (_Float16)(v - (float)hi);
}

// =====================================================================
__global__ void prep_kernel(
    const float* __restrict__ ew1, const float* __restrict__ ew2,
    const float* __restrict__ ew3, const float* __restrict__ cb,
    const float* __restrict__ dw1, const float* __restrict__ dw2,
    const float* __restrict__ dw3, char* __restrict__ wsb) {
  _Float16* w1m = (_Float16*)(wsb + W1M_O);
  _Float16* w1r = (_Float16*)(wsb + W1R_O);
  _Float16* e2m = (_Float16*)(wsb + E2M_O);
  _Float16* e2r = (_Float16*)(wsb + E2R_O);
  _Float16* e3m = (_Float16*)(wsb + E3M_O);
  _Float16* e3r = (_Float16*)(wsb + E3R_O);
  _Float16* cbm = (_Float16*)(wsb + CBM_O);
  _Float16* cbr = (_Float16*)(wsb + CBR_O);
  _Float16* d1p = (_Float16*)(wsb + D1P_O);
  _Float16* d2p = (_Float16*)(wsb + D2P_O);
  _Float16* d3p = (_Float16*)(wsb + D3P_O);
  float* cn = (float*)(wsb + CN_O);

  const int gid = blockIdx.x * 256 + threadIdx.x;
  const int stride = gridDim.x * 256;
  for (int e = gid; e < 256 * 32; e += stride) {
    int n = e >> 5, k = e & 31;
    float v = (k < 9) ? ew1[n * 9 + k] : 0.f;
    split2(v, w1m[e], w1r[e]);
  }
  for (int e = gid; e < 128 * 256; e += stride) split2(ew2[e], e2m[e], e2r[e]);
  for (int e = gid; e < 64 * 128; e += stride) split2(ew3[e], e3m[e], e3r[e]);
  for (int e = gid; e < 1024 * 64; e += stride) split2(cb[e], cbm[e], cbr[e]);
  for (int e = gid; e < 128 * 64; e += stride) d1p[e] = (_Float16)dw1[e];
  for (int e = gid; e < 256 * 128; e += stride) d2p[e] = (_Float16)dw2[e];
  for (int e = gid; e < 16 * 256; e += stride) {
    int n = e >> 8, k = e & 255;
    d3p[e] = (n < 9) ? (_Float16)dw3[n * 256 + k] : (_Float16)0.f;
  }
  for (int i = gid; i < 1024; i += stride) {
    float s = 0.f;
    const float* c = cb + (size_t)i * 64;
#pragma unroll 8
    for (int k = 0; k < 64; ++k) s = fmaf(c[k], c[k], s);
    cn[i] = s;
  }
}

// =====================================================================
// Megakernel: 128 rows/block, 4 waves, 2 row-tiles/wave, LDS staging with
// T14 async split (regs carry next chunk across the compute phase).
__global__ __launch_bounds__(256, 3) void vqvae_mega(
    const float* __restrict__ x,
    const float* __restrict__ eb1, const float* __restrict__ eb2,
    const float* __restrict__ eb3, const float* __restrict__ db1,
    const float* __restrict__ db2, const float* __restrict__ db3,
    const float* __restrict__ cb, const char* __restrict__ wsb,
    float* __restrict__ out, int* __restrict__ idx_g, float* __restrict__ esp_g) {
  __shared__ _Float16 LP[20480];  // 40960 B: [0..10239] staging, [10240..] WPS

  const int t = threadIdx.x;
  const int lane = t & 63;
  const int w = t >> 6;
  const int m = lane & 15;
  const int q = lane >> 4;
  const int R0 = blockIdx.x * 128;
  const int wr0 = 32 * w;
  _Float16* WPS = LP + 10240 + w * 2560;
  const float* cn_g = (const float*)(wsb + CN_O);

  half8 axm[2] = {{}, {}}, axr[2] = {{}, {}};
#pragma unroll
  for (int rt = 0; rt < 2; ++rt) {
    const int grow = R0 + wr0 + 16 * rt + m;
    if (q == 0) {
#pragma unroll
      for (int j = 0; j < 8; ++j) {
        const float v = x[(size_t)grow * 9 + j];
        const _Float16 hi = (_Float16)v;
        axm[rt][j] = hi;
        axr[rt][j] = (_Float16)(v - (float)hi);
      }
    } else if (q == 1) {
      const float v = x[(size_t)grow * 9 + 8];
      const _Float16 hi = (_Float16)v;
      axm[rt][0] = hi;
      axr[rt][0] = (_Float16)(v - (float)hi);
    }
  }

  // ================= Stage A: enc1 fused with enc2 (staged W2, T14 pipeline)
  floatx4 acc2[8][2];
#pragma unroll
  for (int nt = 0; nt < 8; ++nt)
#pragma unroll
    for (int rt = 0; rt < 2; ++rt) acc2[nt][rt] = (floatx4){0.f, 0.f, 0.f, 0.f};

  {
    const int pA = t >> 7, nA = t & 127;
    const char* srcA = wsb + (pA ? E2R_O : E2M_O) + (size_t)nA * 512;
    _Float16* dstA = LP + (pA ? 5120 : 0) + nA * 40;
    half8 stg[4];
#pragma unroll
    for (int j = 0; j < 4; ++j) stg[j] = *(const half8*)(srcA + j * 16);

    for (int kc = 0; kc < 8; ++kc) {
      VMCNT0();  // stg for chunk kc has landed (covered by prev compute)
#pragma unroll
      for (int j = 0; j < 4; ++j) *(half8*)(dstA + j * 8) = stg[j];
      LDS_FENCE();  // writes landed before barrier
      if (kc < 7) {
#pragma unroll
        for (int j = 0; j < 4; ++j)
          stg[j] = *(const half8*)(srcA + (size_t)(kc + 1) * 64 + j * 16);
      }
      BARRIER();  // staged chunk visible; prefetch stays in flight

#pragma unroll
      for (int ntl = 0; ntl < 2; ++ntl) {
        const int f = kc * 32 + ntl * 16 + m;
        const half8 bm = *(const half8*)(wsb + W1M_O + (size_t)f * 64 + q * 16);
        const half8 br = *(const half8*)(wsb + W1R_O + (size_t)f * 64 + q * 16);
        const float bias = eb1[f];
#pragma unroll
        for (int rt = 0; rt < 2; ++rt) {
          floatx4 a = (floatx4){0.f, 0.f, 0.f, 0.f};
          a = MFMA16(axr[rt], bm, a);
          a = MFMA16(axm[rt], br, a);
          a = MFMA16(axm[rt], bm, a);
#pragma unroll
          for (int reg = 0; reg < 4; ++reg) {
            const float v = fmaxf(a[reg] + bias, 0.f);
            const int row = 16 * rt + 4 * q + reg;
            const _Float16 hi = (_Float16)v;
            WPS[row * 40 + ntl * 16 + m] = hi;
            WPS[1280 + row * 40 + ntl * 16 + m] = (_Float16)(v - (float)hi);
          }
        }
      }
      LDS_FENCE();
      half8 am[2], ar[2];
#pragma unroll
      for (int rt = 0; rt < 2; ++rt) {
        am[rt] = *(const half8*)(WPS + (16 * rt + m) * 40 + q * 8);
        ar[rt] = *(const half8*)(WPS + 1280 + (16 * rt + m) * 40 + q * 8);
      }
#pragma unroll
      for (int nt = 0; nt < 8; ++nt) {
        const half8 bm = *(const half8*)(LP + (nt * 16 + m) * 40 + q * 8);
        const half8 br = *(const half8*)(LP + 5120 + (nt * 16 + m) * 40 + q * 8);
#pragma unroll
        for (int rt = 0; rt < 2; ++rt) {
          acc2[nt][rt] = MFMA16(ar[rt], bm, acc2[nt][rt]);
          acc2[nt][rt] = MFMA16(am[rt], br, acc2[nt][rt]);
          acc2[nt][rt] = MFMA16(am[rt], bm, acc2[nt][rt]);
        }
      }
      BARRIER();  // all staged reads done -> next chunk may overwrite
    }
  }

  // ================= Stage B: enc3 (B direct from L2; H2 via wave scratch)
  floatx4 acc3[4][2];
#pragma unroll
  for (int nt = 0; nt < 4; ++nt)
#pragma unroll
    for (int rt = 0; rt < 2; ++rt) acc3[nt][rt] = (floatx4){0.f, 0.f, 0.f, 0.f};

  for (int ks = 0; ks < 4; ++ks) {
#pragma unroll
    for (int h = 0; h < 2; ++h) {
      const int nt = 2 * ks + h;
      const float bias = eb2[nt * 16 + m];
#pragma unroll
      for (int rt = 0; rt < 2; ++rt) {
#pragma unroll
        for (int reg = 0; reg < 4; ++reg) {
          const float v = fmaxf(acc2[nt][rt][reg] + bias, 0.f);
          const int row = 16 * rt + 4 * q + reg;
          const _Float16 hi = (_Float16)v;
          WPS[row * 40 + h * 16 + m] = hi;
          WPS[1280 + row * 40 + h * 16 + m] = (_Float16)(v - (float)hi);
        }
      }
    }
    LDS_FENCE();
    half8 am[2], ar[2];
#pragma unroll
    for (int rt = 0; rt < 2; ++rt) {
      am[rt] = *(const half8*)(WPS + (16 * rt + m) * 40 + q * 8);
      ar[rt] = *(const half8*)(WPS + 1280 + (16 * rt + m) * 40 + q * 8);
    }
#pragma unroll
    for (int nt = 0; nt < 4; ++nt) {
      const half8 bm = *(const half8*)(wsb + E3M_O + (size_t)(nt * 16 + m) * 256 + ks * 64 + q * 16);
      const half8 br = *(const half8*)(wsb + E3R_O + (size_t)(nt * 16 + m) * 256 + ks * 64 + q * 16);
#pragma unroll
      for (int rt = 0; rt < 2; ++rt) {
        acc3[nt][rt] = MFMA16(ar[rt], bm, acc3[nt][rt]);
        acc3[nt][rt] = MFMA16(am[rt], br, acc3[nt][rt]);
        acc3[nt][rt] = MFMA16(am[rt], bm, acc3[nt][rt]);
      }
    }
  }

  // ---- Stage C prologue: issue chunk-0 codebook loads (hide under Z epilogue)
  const int pC = t >> 7, eC = t & 127;
  const int nC = eC >> 1, hC = eC & 1;
  const char* srcC = wsb + (pC ? CBR_O : CBM_O) + (size_t)nC * 128 + hC * 64;
  _Float16* dstC = LP + (pC ? 4608 : 0) + nC * 72 + hC * 32;
  half8 stgC[4];
#pragma unroll
  for (int j = 0; j < 4; ++j) stgC[j] = *(const half8*)(srcC + j * 16);

  // ---- Z epilogue -> register fragments (no ||z||^2 needed for argmin)
  half8 zfm[2][2], zfr[2][2];
#pragma unroll
  for (int rt = 0; rt < 2; ++rt) {
#pragma unroll
    for (int nt = 0; nt < 4; ++nt) {
      const float bias = eb3[nt * 16 + m];
#pragma unroll
      for (int reg = 0; reg < 4; ++reg) {
        const float v = acc3[nt][rt][reg] + bias;
        const int row = 4 * q + reg;
        const _Float16 hi = (_Float16)v;
        WPS[row * 72 + nt * 16 + m] = hi;
        WPS[1152 + row * 72 + nt * 16 + m] = (_Float16)(v - (float)hi);
      }
    }
    LDS_FENCE();
#pragma unroll
    for (int ks2 = 0; ks2 < 2; ++ks2) {
      zfm[rt][ks2] = *(const half8*)(WPS + m * 72 + ks2 * 32 + q * 8);
      zfr[rt][ks2] = *(const half8*)(WPS + 1152 + m * 72 + ks2 * 32 + q * 8);
    }
  }

  // ================= Stage C: VQ argmax-score (staged CB, T14 pipeline,
  // cnv folded into accumulator init: score = dot - 0.5||c||^2)
  float bests[2][4];
  int besti[2][4];
#pragma unroll
  for (int rt = 0; rt < 2; ++rt)
#pragma unroll
    for (int reg = 0; reg < 4; ++reg) { bests[rt][reg] = -3.4e38f; besti[rt][reg] = 0; }

  for (int cc = 0; cc < 16; ++cc) {
    VMCNT0();
#pragma unroll
    for (int j = 0; j < 4; ++j) *(half8*)(dstC + j * 8) = stgC[j];
    LDS_FENCE();
    if (cc < 15) {
#pragma unroll
      for (int j = 0; j < 4; ++j)
        stgC[j] = *(const half8*)(srcC + (size_t)(cc + 1) * 8192 + j * 16);
    }
    BARRIER();

    floatx4 accd[4][2];
#pragma unroll
    for (int nt = 0; nt < 4; ++nt) {
      const float ci = -0.5f * cn_g[cc * 64 + nt * 16 + m];
#pragma unroll
      for (int rt = 0; rt < 2; ++rt) accd[nt][rt] = (floatx4){ci, ci, ci, ci};
    }
#pragma unroll
    for (int nt = 0; nt < 4; ++nt) {
#pragma unroll
      for (int ks2 = 0; ks2 < 2; ++ks2) {
        const half8 bm = *(const half8*)(LP + (nt * 16 + m) * 72 + ks2 * 32 + q * 8);
        const half8 br = *(const half8*)(LP + 4608 + (nt * 16 + m) * 72 + ks2 * 32 + q * 8);
#pragma unroll
        for (int rt = 0; rt < 2; ++rt) {
          accd[nt][rt] = MFMA16(zfr[rt][ks2], bm, accd[nt][rt]);
          accd[nt][rt] = MFMA16(zfm[rt][ks2], br, accd[nt][rt]);
          accd[nt][rt] = MFMA16(zfm[rt][ks2], bm, accd[nt][rt]);
        }
      }
    }
#pragma unroll
    for (int nt = 0; nt < 4; ++nt) {
      const int code = cc * 64 + nt * 16 + m;
#pragma unroll
      for (int rt = 0; rt < 2; ++rt) {
#pragma unroll
        for (int reg = 0; reg < 4; ++reg) {
          const float s = accd[nt][rt][reg];  // maximize
          if (s > bests[rt][reg]) { bests[rt][reg] = s; besti[rt][reg] = code; }
        }
      }
    }
    BARRIER();
  }
#pragma unroll
  for (int rt = 0; rt < 2; ++rt) {
#pragma unroll
    for (int reg = 0; reg < 4; ++reg) {
#pragma unroll
      for (int off = 1; off < 16; off <<= 1) {
        const float os = __shfl_xor(bests[rt][reg], off, 16);
        const int oi = __shfl_xor(besti[rt][reg], off, 16);
        if (os > bests[rt][reg] || (os == bests[rt][reg] && oi < besti[rt][reg])) {
          bests[rt][reg] = os; besti[rt][reg] = oi;
        }
      }
    }
  }
  if (m == 0) {
#pragma unroll
    for (int rt = 0; rt < 2; ++rt)
#pragma unroll
      for (int reg = 0; reg < 4; ++reg) {
        const int row = wr0 + 16 * rt + 4 * q + reg;
        idx_g[R0 + row] = besti[rt][reg];  // plain store; hist kernel follows
      }
  }

  // ---- z_q (straight-through) + per-wave e_latent partial.
  // Shuffle broadcast: after the width-16 butterfly ALL lanes in a 16-group
  // hold that group's argmin for (rt, reg). Row 16rt+m -> group m>>2, reg m&3.
  const int sl = ((m >> 2) << 4) | m;  // any lane of group m>>2
  half8 zq[2][2];
  float es = 0.f;
#pragma unroll
  for (int rt = 0; rt < 2; ++rt) {
    const int b0 = __shfl(besti[rt][0], sl);
    const int b1 = __shfl(besti[rt][1], sl);
    const int b2 = __shfl(besti[rt][2], sl);
    const int b3 = __shfl(besti[rt][3], sl);
    const int r2 = m & 3;
    const int bi = (r2 == 0) ? b0 : (r2 == 1) ? b1 : (r2 == 2) ? b2 : b3;
#pragma unroll
    for (int ks2 = 0; ks2 < 2; ++ks2) {
      const float* cp = cb + (size_t)bi * 64 + ks2 * 32 + q * 8;
      const float4 c0 = *(const float4*)cp;
      const float4 c1 = *(const float4*)(cp + 4);
      float cv[8] = {c0.x, c0.y, c0.z, c0.w, c1.x, c1.y, c1.z, c1.w};
#pragma unroll
      for (int j = 0; j < 8; ++j) {
        const float z = (float)zfm[rt][ks2][j] + (float)zfr[rt][ks2][j];
        const float d = cv[j] - z;
        es = fmaf(d, d, es);
        zq[rt][ks2][j] = (_Float16)(z + d);
      }
    }
  }
#pragma unroll
  for (int off = 1; off < 64; off <<= 1) es += __shfl_xor(es, off, 64);
  if (lane == 0) esp_g[blockIdx.x * 4 + w] = es;  // no atomic

  // ---- Stage E prologue: issue chunk-0 WD2 loads (hide under stage D)
  const int nE = t >> 2, jE = t & 3;
  const char* srcE = wsb + D2P_O + (size_t)nE * 256 + jE * 64;
  _Float16* dstE = LP + nE * 136 + jE * 32;
  half8 stgE[4];
#pragma unroll
  for (int j = 0; j < 4; ++j) stgE[j] = *(const half8*)(srcE + j * 16);

  // ================= Stage D: dec1 (plain fp16, B direct)
  floatx4 accH[8][2];
#pragma unroll
  for (int nt = 0; nt < 8; ++nt)
#pragma unroll
    for (int rt = 0; rt < 2; ++rt) accH[nt][rt] = (floatx4){0.f, 0.f, 0.f, 0.f};
#pragma unroll
  for (int nt = 0; nt < 8; ++nt) {
#pragma unroll
    for (int ks2 = 0; ks2 < 2; ++ks2) {
      const half8 b = *(const half8*)(wsb + D1P_O + (size_t)(nt * 16 + m) * 128 + ks2 * 64 + q * 16);
#pragma unroll
      for (int rt = 0; rt < 2; ++rt) accH[nt][rt] = MFMA16(zq[rt][ks2], b, accH[nt][rt]);
    }
  }
  half8 h3f[2][4];
  for (int ks = 0; ks < 4; ++ks) {
#pragma unroll
    for (int h = 0; h < 2; ++h) {
      const int nt = 2 * ks + h;
      const float bias = db1[nt * 16 + m];
#pragma unroll
      for (int rt = 0; rt < 2; ++rt)
#pragma unroll
        for (int reg = 0; reg < 4; ++reg) {
          const float v = fmaxf(accH[nt][rt][reg] + bias, 0.f);
          WPS[(16 * rt + 4 * q + reg) * 40 + h * 16 + m] = (_Float16)v;
        }
    }
    LDS_FENCE();
#pragma unroll
    for (int rt = 0; rt < 2; ++rt)
      h3f[rt][ks] = *(const half8*)(WPS + (16 * rt + m) * 40 + q * 8);
  }

  // ================= Stage E: dec2 (staged WD2, T14 pipeline) fused w/ dec3
  floatx4 accO[2] = {(floatx4){0.f, 0.f, 0.f, 0.f}, (floatx4){0.f, 0.f, 0.f, 0.f}};
  for (int jc = 0; jc < 4; ++jc) {
    VMCNT0();
#pragma unroll
    for (int j = 0; j < 4; ++j) *(half8*)(dstE + j * 8) = stgE[j];
    LDS_FENCE();
    if (jc < 3) {
#pragma unroll
      for (int j = 0; j < 4; ++j)
        stgE[j] = *(const half8*)(srcE + (size_t)(jc + 1) * 16384 + j * 16);
    }
    BARRIER();

    floatx4 accD2[4][2];
#pragma unroll
    for (int nt = 0; nt < 4; ++nt)
#pragma unroll
      for (int rt = 0; rt < 2; ++rt) accD2[nt][rt] = (floatx4){0.f, 0.f, 0.f, 0.f};
#pragma unroll
    for (int nt = 0; nt < 4; ++nt) {
#pragma unroll
      for (int ks = 0; ks < 4; ++ks) {
        const half8 b = *(const half8*)(LP + (nt * 16 + m) * 136 + ks * 32 + q * 8);
#pragma unroll
        for (int rt = 0; rt < 2; ++rt) accD2[nt][rt] = MFMA16(h3f[rt][ks], b, accD2[nt][rt]);
      }
    }
    half8 b3[2];
#pragma unroll
    for (int ks2 = 0; ks2 < 2; ++ks2)
      b3[ks2] = *(const half8*)(wsb + D3P_O + (size_t)m * 512 + jc * 128 + ks2 * 64 + q * 16);
#pragma unroll
    for (int rt = 0; rt < 2; ++rt) {
#pragma unroll
      for (int nt = 0; nt < 4; ++nt) {
        const float bias = db2[jc * 64 + nt * 16 + m];
#pragma unroll
        for (int reg = 0; reg < 4; ++reg) {
          const float v = fmaxf(accD2[nt][rt][reg] + bias, 0.f);
          WPS[(4 * q + reg) * 72 + nt * 16 + m] = (_Float16)v;
        }
      }
      LDS_FENCE();
#pragma unroll
      for (int ks2 = 0; ks2 < 2; ++ks2) {
        const half8 am = *(const half8*)(WPS + m * 72 + ks2 * 32 + q * 8);
        accO[rt] = MFMA16(am, b3[ks2], accO[rt]);
      }
    }
    BARRIER();
  }
  if (m < 9) {
    const float bias = db3[m];
#pragma unroll
    for (int rt = 0; rt < 2; ++rt)
#pragma unroll
      for (int reg = 0; reg < 4; ++reg) {
        const size_t r = (size_t)(R0 + wr0 + 16 * rt + 4 * q + reg);
        out[r * 9 + m] = accO[rt][reg] + bias;
      }
  }
}

// =====================================================================
__global__ __launch_bounds__(256) void hist_kernel(
    const int* __restrict__ idx_g, int* __restrict__ hp) {
  __shared__ int lh[1024];
  const int t = threadIdx.x;
#pragma unroll
  for (int i = 0; i < 4; ++i) lh[t * 4 + i] = 0;
  __syncthreads();
  for (int i = t; i < 4096; i += 256)
    atomicAdd(&lh[idx_g[blockIdx.x * 4096 + i]], 1);  // LDS atomic only
  __syncthreads();
  int* part = hp + blockIdx.x * 1024;
#pragma unroll
  for (int i = 0; i < 4; ++i) part[t * 4 + i] = lh[t * 4 + i];
}

// =====================================================================
__global__ __launch_bounds__(1024) void finalize_kernel(
    const int* __restrict__ hp, const float* __restrict__ esp,
    float* __restrict__ out2) {
  __shared__ double red[1024];
  __shared__ float rede[1024];
  const int t = threadIdx.x;
  int h = 0;
#pragma unroll 8
  for (int p = 0; p < 64; ++p) h += hp[p * 1024 + t];
  const float pr = (float)h * (1.0f / (float)kN);
  red[t] = (double)(pr * logf(pr + 1e-10f));
  float es = 0.f;
#pragma unroll
  for (int i = 0; i < 8; ++i) es += esp[i * 1024 + t];
  rede[t] = es;
  __syncthreads();
  for (int s = 512; s > 0; s >>= 1) {
    if (t < s) { red[t] += red[t + s]; rede[t] += rede[t + s]; }
    __syncthreads();
  }
  if (t == 0) {
    out2[0] = 1.25f * (rede[0] * (1.0f / ((float)kN * 64.0f)));
    out2[1] = expf((float)(-red[0]));
  }
}

}  // namespace

extern "C" void kernel_launch(void* const* d_in, const int* in_sizes, int n_in,
                              void* d_out, int out_size, void* d_ws, size_t ws_size,
                              hipStream_t stream) {
  const float* x   = (const float*)d_in[0];
  const float* ew1 = (const float*)d_in[1];
  const float* eb1 = (const float*)d_in[2];
  const float* ew2 = (const float*)d_in[3];
  const float* eb2 = (const float*)d_in[4];
  const float* ew3 = (const float*)d_in[5];
  const float* eb3 = (const float*)d_in[6];
  const float* dw1 = (const float*)d_in[7];
  const float* db1 = (const float*)d_in[8];
  const float* dw2 = (const float*)d_in[9];
  const float* db2 = (const float*)d_in[10];
  const float* dw3 = (const float*)d_in[11];
  const float* db3 = (const float*)d_in[12];
  const float* cb  = (const float*)d_in[13];
  float* out = (float*)d_out;
  char* wsb = (char*)d_ws;

  int* idx_g = (int*)(wsb + IDX_O);
  float* esp = (float*)(wsb + ESP_O);
  int* hp = (int*)(wsb + HP_O);

  prep_kernel<<<128, 256, 0, stream>>>(ew1, ew2, ew3, cb, dw1, dw2, dw3, wsb);
  vqvae_mega<<<kN / 128, 256, 0, stream>>>(x, eb1, eb2, eb3, db1, db2, db3, cb,
                                           wsb, out, idx_g, esp);
  hist_kernel<<<64, 256, 0, stream>>>(idx_g, hp);
  finalize_kernel<<<1, 1024, 0, stream>>>(hp, esp, out + (size_t)kN * 9);
}

// Round 15
// 322.241 us; speedup vs baseline: 1.5409x; 1.0005x over previous
//
#include <hip/hip_runtime.h>
#include <math.h>

// VQVAE forward — R20 (resubmit; R14-round bench = GPUAcquisitionTimeout,
// no data). R19 mega (unchanged, 260.7us, plateau-proven) + tail collapse.
// Counter blind spot: mega=260.8 vs total=322.4 -> 61.6us (19%) in
// prep/hist/finalize/gaps, never profiled (top-5 = all mega). finalize was
// a SINGLE block doing 64 latency-bound strided rounds over 256KB of hp
// partials (~12-18us, zero TLP). R20: hist blocks atomicAdd their LDS
// histograms into ONE global 1024-bin hist (64 adds/address — guideline-12
// clean; NOT the per-row 262k-atomic ~450us floor), then a no-spin ticket
// (threadfence + device atomicAdd; grid 64 << 256 CUs) elects the last
// block to compute entropy (reads via atomicAdd(p,0) for cross-XCD
// coherence) + es sum + outputs. finalize kernel and hp round-trip deleted
// (4 -> 3 dispatches). prep zeroes gh[0..1024] (incl. cnt at GH_O+4096)
// each iteration — stream-ordered before hist; graph-replay safe.
// Numerics: double-entropy accumulation order (~1e-15), es f32 order
// (~1e-6) — both << tolerance. Mega kernel bit-identical to R19.

namespace {

constexpr int kN = 262144;

typedef _Float16 half8 __attribute__((ext_vector_type(8)));
typedef float floatx4 __attribute__((ext_vector_type(4)));

#define MFMA16(a, b, c) __builtin_amdgcn_mfma_f32_16x16x32_f16((a), (b), (c), 0, 0, 0)
#define LDS_FENCE() asm volatile("s_waitcnt lgkmcnt(0)" ::: "memory")
#define VMCNT0() asm volatile("s_waitcnt vmcnt(0)" ::: "memory")
#define BARRIER()                                  \
  do {                                             \
    asm volatile("" ::: "memory");                 \
    __builtin_amdgcn_s_barrier();                  \
    asm volatile("" ::: "memory");                 \
  } while (0)

// ---- workspace byte offsets (weights region, as R4-R19)
constexpr size_t W1M_O = 0;        // ew1 padded [256][32] f16 (k>=9 zero), main
constexpr size_t W1R_O = 16384;    // residual
constexpr size_t E2M_O = 32768;    // ew2 [128][256]
constexpr size_t E2R_O = 98304;
constexpr size_t E3M_O = 163840;   // ew3 [64][128]
constexpr size_t E3R_O = 180224;
constexpr size_t CBM_O = 196608;   // codebook [1024][64]
constexpr size_t CBR_O = 327680;
constexpr size_t D1P_O = 458752;   // dw1 [128][64] plain
constexpr size_t D2P_O = 475136;   // dw2 [256][128] plain
constexpr size_t D3P_O = 540672;   // dw3 padded [16][256] plain
constexpr size_t CN_O  = 548864;   // cn [1024] f32
// ---- small outputs
constexpr size_t IDX_O = 589824;             // idx [N] i32 (1 MB)
constexpr size_t ESP_O = IDX_O + 1048576;    // es partials [8192] f32
constexpr size_t GH_O  = ESP_O + 32768;      // global hist [1024] i32
constexpr size_t CNT_O = GH_O + 4096;        // ticket counter [1] i32

__device__ __forceinline__ void split2(float v, _Float16& hi, _Float16& lo) {
  hi = (_Float16)v;
  lo = (_Float16)(v - (float)hi);
}

// =====================================================================
__global__ void prep_kernel(
    const float* __restrict__ ew1, const float* __restrict__ ew2,
    const float* __restrict__ ew3, const float* __restrict__ cb,
    const float* __restrict__ dw1, const float* __restrict__ dw2,
    const float* __restrict__ dw3, char* __restrict__ wsb) {
  _Float16* w1m = (_Float16*)(wsb + W1M_O);
  _Float16* w1r = (_Float16*)(wsb + W1R_O);
  _Float16* e2m = (_Float16*)(wsb + E2M_O);
  _Float16* e2r = (_Float16*)(wsb + E2R_O);
  _Float16* e3m = (_Float16*)(wsb + E3M_O);
  _Float16* e3r = (_Float16*)(wsb + E3R_O);
  _Float16* cbm = (_Float16*)(wsb + CBM_O);
  _Float16* cbr = (_Float16*)(wsb + CBR_O);
  _Float16* d1p = (_Float16*)(wsb + D1P_O);
  _Float16* d2p = (_Float16*)(wsb + D2P_O);
  _Float16* d3p = (_Float16*)(wsb + D3P_O);
  float* cn = (float*)(wsb + CN_O);
  int* gh = (int*)(wsb + GH_O);

  const int gid = blockIdx.x * 256 + threadIdx.x;
  const int stride = gridDim.x * 256;
  // zero global hist + ticket counter (graph-replay safe: stream-ordered)
  for (int i = gid; i < 1025; i += stride) gh[i] = 0;
  for (int e = gid; e < 256 * 32; e += stride) {
    int n = e >> 5, k = e & 31;
    float v = (k < 9) ? ew1[n * 9 + k] : 0.f;
    split2(v, w1m[e], w1r[e]);
  }
  for (int e = gid; e < 128 * 256; e += stride) split2(ew2[e], e2m[e], e2r[e]);
  for (int e = gid; e < 64 * 128; e += stride) split2(ew3[e], e3m[e], e3r[e]);
  for (int e = gid; e < 1024 * 64; e += stride) split2(cb[e], cbm[e], cbr[e]);
  for (int e = gid; e < 128 * 64; e += stride) d1p[e] = (_Float16)dw1[e];
  for (int e = gid; e < 256 * 128; e += stride) d2p[e] = (_Float16)dw2[e];
  for (int e = gid; e < 16 * 256; e += stride) {
    int n = e >> 8, k = e & 255;
    d3p[e] = (n < 9) ? (_Float16)dw3[n * 256 + k] : (_Float16)0.f;
  }
  for (int i = gid; i < 1024; i += stride) {
    float s = 0.f;
    const float* c = cb + (size_t)i * 64;
#pragma unroll 8
    for (int k = 0; k < 64; ++k) s = fmaf(c[k], c[k], s);
    cn[i] = s;
  }
}

// =====================================================================
// Megakernel: 128 rows/block, 4 waves, 2 row-tiles/wave, LDS staging with
// T14 async split (regs carry next chunk across the compute phase).
// Bit-identical to R19 (measured 260.7us).
__global__ __launch_bounds__(256, 3) void vqvae_mega(
    const float* __restrict__ x,
    const float* __restrict__ eb1, const float* __restrict__ eb2,
    const float* __restrict__ eb3, const float* __restrict__ db1,
    const float* __restrict__ db2, const float* __restrict__ db3,
    const float* __restrict__ cb, const char* __restrict__ wsb,
    float* __restrict__ out, int* __restrict__ idx_g, float* __restrict__ esp_g) {
  __shared__ _Float16 LP[20480];  // 40960 B: [0..10239] staging, [10240..] WPS

  const int t = threadIdx.x;
  const int lane = t & 63;
  const int w = t >> 6;
  const int m = lane & 15;
  const int q = lane >> 4;
  const int R0 = blockIdx.x * 128;
  const int wr0 = 32 * w;
  _Float16* WPS = LP + 10240 + w * 2560;
  const float* cn_g = (const float*)(wsb + CN_O);

  half8 axm[2] = {{}, {}}, axr[2] = {{}, {}};
#pragma unroll
  for (int rt = 0; rt < 2; ++rt) {
    const int grow = R0 + wr0 + 16 * rt + m;
    if (q == 0) {
#pragma unroll
      for (int j = 0; j < 8; ++j) {
        const float v = x[(size_t)grow * 9 + j];
        const _Float16 hi = (_Float16)v;
        axm[rt][j] = hi;
        axr[rt][j] = (_Float16)(v - (float)hi);
      }
    } else if (q == 1) {
      const float v = x[(size_t)grow * 9 + 8];
      const _Float16 hi = (_Float16)v;
      axm[rt][0] = hi;
      axr[rt][0] = (_Float16)(v - (float)hi);
    }
  }

  // ================= Stage A: enc1 fused with enc2 (staged W2, T14 pipeline)
  floatx4 acc2[8][2];
#pragma unroll
  for (int nt = 0; nt < 8; ++nt)
#pragma unroll
    for (int rt = 0; rt < 2; ++rt) acc2[nt][rt] = (floatx4){0.f, 0.f, 0.f, 0.f};

  {
    const int pA = t >> 7, nA = t & 127;
    const char* srcA = wsb + (pA ? E2R_O : E2M_O) + (size_t)nA * 512;
    _Float16* dstA = LP + (pA ? 5120 : 0) + nA * 40;
    half8 stg[4];
#pragma unroll
    for (int j = 0; j < 4; ++j) stg[j] = *(const half8*)(srcA + j * 16);

    for (int kc = 0; kc < 8; ++kc) {
      VMCNT0();  // stg for chunk kc has landed (covered by prev compute)
#pragma unroll
      for (int j = 0; j < 4; ++j) *(half8*)(dstA + j * 8) = stg[j];
      LDS_FENCE();  // writes landed before barrier
      if (kc < 7) {
#pragma unroll
        for (int j = 0; j < 4; ++j)
          stg[j] = *(const half8*)(srcA + (size_t)(kc + 1) * 64 + j * 16);
      }
      BARRIER();  // staged chunk visible; prefetch stays in flight

#pragma unroll
      for (int ntl = 0; ntl < 2; ++ntl) {
        const int f = kc * 32 + ntl * 16 + m;
        const half8 bm = *(const half8*)(wsb + W1M_O + (size_t)f * 64 + q * 16);
        const half8 br = *(const half8*)(wsb + W1R_O + (size_t)f * 64 + q * 16);
        const float bias = eb1[f];
#pragma unroll
        for (int rt = 0; rt < 2; ++rt) {
          floatx4 a = (floatx4){0.f, 0.f, 0.f, 0.f};
          a = MFMA16(axr[rt], bm, a);
          a = MFMA16(axm[rt], br, a);
          a = MFMA16(axm[rt], bm, a);
#pragma unroll
          for (int reg = 0; reg < 4; ++reg) {
            const float v = fmaxf(a[reg] + bias, 0.f);
            const int row = 16 * rt + 4 * q + reg;
            const _Float16 hi = (_Float16)v;
            WPS[row * 40 + ntl * 16 + m] = hi;
            WPS[1280 + row * 40 + ntl * 16 + m] = (_Float16)(v - (float)hi);
          }
        }
      }
      LDS_FENCE();
      half8 am[2], ar[2];
#pragma unroll
      for (int rt = 0; rt < 2; ++rt) {
        am[rt] = *(const half8*)(WPS + (16 * rt + m) * 40 + q * 8);
        ar[rt] = *(const half8*)(WPS + 1280 + (16 * rt + m) * 40 + q * 8);
      }
#pragma unroll
      for (int nt = 0; nt < 8; ++nt) {
        const half8 bm = *(const half8*)(LP + (nt * 16 + m) * 40 + q * 8);
        const half8 br = *(const half8*)(LP + 5120 + (nt * 16 + m) * 40 + q * 8);
#pragma unroll
        for (int rt = 0; rt < 2; ++rt) {
          acc2[nt][rt] = MFMA16(ar[rt], bm, acc2[nt][rt]);
          acc2[nt][rt] = MFMA16(am[rt], br, acc2[nt][rt]);
          acc2[nt][rt] = MFMA16(am[rt], bm, acc2[nt][rt]);
        }
      }
      BARRIER();  // all staged reads done -> next chunk may overwrite
    }
  }

  // ================= Stage B: enc3 (B direct from L2; H2 via wave scratch)
  floatx4 acc3[4][2];
#pragma unroll
  for (int nt = 0; nt < 4; ++nt)
#pragma unroll
    for (int rt = 0; rt < 2; ++rt) acc3[nt][rt] = (floatx4){0.f, 0.f, 0.f, 0.f};

  for (int ks = 0; ks < 4; ++ks) {
#pragma unroll
    for (int h = 0; h < 2; ++h) {
      const int nt = 2 * ks + h;
      const float bias = eb2[nt * 16 + m];
#pragma unroll
      for (int rt = 0; rt < 2; ++rt) {
#pragma unroll
        for (int reg = 0; reg < 4; ++reg) {
          const float v = fmaxf(acc2[nt][rt][reg] + bias, 0.f);
          const int row = 16 * rt + 4 * q + reg;
          const _Float16 hi = (_Float16)v;
          WPS[row * 40 + h * 16 + m] = hi;
          WPS[1280 + row * 40 + h * 16 + m] = (_Float16)(v - (float)hi);
        }
      }
    }
    LDS_FENCE();
    half8 am[2], ar[2];
#pragma unroll
    for (int rt = 0; rt < 2; ++rt) {
      am[rt] = *(const half8*)(WPS + (16 * rt + m) * 40 + q * 8);
      ar[rt] = *(const half8*)(WPS + 1280 + (16 * rt + m) * 40 + q * 8);
    }
#pragma unroll
    for (int nt = 0; nt < 4; ++nt) {
      const half8 bm = *(const half8*)(wsb + E3M_O + (size_t)(nt * 16 + m) * 256 + ks * 64 + q * 16);
      const half8 br = *(const half8*)(wsb + E3R_O + (size_t)(nt * 16 + m) * 256 + ks * 64 + q * 16);
#pragma unroll
      for (int rt = 0; rt < 2; ++rt) {
        acc3[nt][rt] = MFMA16(ar[rt], bm, acc3[nt][rt]);
        acc3[nt][rt] = MFMA16(am[rt], br, acc3[nt][rt]);
        acc3[nt][rt] = MFMA16(am[rt], bm, acc3[nt][rt]);
      }
    }
  }

  // ---- Stage C prologue: issue chunk-0 codebook loads (hide under Z epilogue)
  const int pC = t >> 7, eC = t & 127;
  const int nC = eC >> 1, hC = eC & 1;
  const char* srcC = wsb + (pC ? CBR_O : CBM_O) + (size_t)nC * 128 + hC * 64;
  _Float16* dstC = LP + (pC ? 4608 : 0) + nC * 72 + hC * 32;
  half8 stgC[4];
#pragma unroll
  for (int j = 0; j < 4; ++j) stgC[j] = *(const half8*)(srcC + j * 16);

  // ---- Z epilogue -> register fragments (no ||z||^2 needed for argmin)
  half8 zfm[2][2], zfr[2][2];
#pragma unroll
  for (int rt = 0; rt < 2; ++rt) {
#pragma unroll
    for (int nt = 0; nt < 4; ++nt) {
      const float bias = eb3[nt * 16 + m];
#pragma unroll
      for (int reg = 0; reg < 4; ++reg) {
        const float v = acc3[nt][rt][reg] + bias;
        const int row = 4 * q + reg;
        const _Float16 hi = (_Float16)v;
        WPS[row * 72 + nt * 16 + m] = hi;
        WPS[1152 + row * 72 + nt * 16 + m] = (_Float16)(v - (float)hi);
      }
    }
    LDS_FENCE();
#pragma unroll
    for (int ks2 = 0; ks2 < 2; ++ks2) {
      zfm[rt][ks2] = *(const half8*)(WPS + m * 72 + ks2 * 32 + q * 8);
      zfr[rt][ks2] = *(const half8*)(WPS + 1152 + m * 72 + ks2 * 32 + q * 8);
    }
  }

  // ================= Stage C: VQ argmax-score (staged CB, T14 pipeline,
  // cnv folded into accumulator init: score = dot - 0.5||c||^2)
  float bests[2][4];
  int besti[2][4];
#pragma unroll
  for (int rt = 0; rt < 2; ++rt)
#pragma unroll
    for (int reg = 0; reg < 4; ++reg) { bests[rt][reg] = -3.4e38f; besti[rt][reg] = 0; }

  for (int cc = 0; cc < 16; ++cc) {
    VMCNT0();
#pragma unroll
    for (int j = 0; j < 4; ++j) *(half8*)(dstC + j * 8) = stgC[j];
    LDS_FENCE();
    if (cc < 15) {
#pragma unroll
      for (int j = 0; j < 4; ++j)
        stgC[j] = *(const half8*)(srcC + (size_t)(cc + 1) * 8192 + j * 16);
    }
    BARRIER();

    floatx4 accd[4][2];
#pragma unroll
    for (int nt = 0; nt < 4; ++nt) {
      const float ci = -0.5f * cn_g[cc * 64 + nt * 16 + m];
#pragma unroll
      for (int rt = 0; rt < 2; ++rt) accd[nt][rt] = (floatx4){ci, ci, ci, ci};
    }
#pragma unroll
    for (int nt = 0; nt < 4; ++nt) {
#pragma unroll
      for (int ks2 = 0; ks2 < 2; ++ks2) {
        const half8 bm = *(const half8*)(LP + (nt * 16 + m) * 72 + ks2 * 32 + q * 8);
        const half8 br = *(const half8*)(LP + 4608 + (nt * 16 + m) * 72 + ks2 * 32 + q * 8);
#pragma unroll
        for (int rt = 0; rt < 2; ++rt) {
          accd[nt][rt] = MFMA16(zfr[rt][ks2], bm, accd[nt][rt]);
          accd[nt][rt] = MFMA16(zfm[rt][ks2], br, accd[nt][rt]);
          accd[nt][rt] = MFMA16(zfm[rt][ks2], bm, accd[nt][rt]);
        }
      }
    }
#pragma unroll
    for (int nt = 0; nt < 4; ++nt) {
      const int code = cc * 64 + nt * 16 + m;
#pragma unroll
      for (int rt = 0; rt < 2; ++rt) {
#pragma unroll
        for (int reg = 0; reg < 4; ++reg) {
          const float s = accd[nt][rt][reg];  // maximize
          if (s > bests[rt][reg]) { bests[rt][reg] = s; besti[rt][reg] = code; }
        }
      }
    }
    BARRIER();
  }
#pragma unroll
  for (int rt = 0; rt < 2; ++rt) {
#pragma unroll
    for (int reg = 0; reg < 4; ++reg) {
#pragma unroll
      for (int off = 1; off < 16; off <<= 1) {
        const float os = __shfl_xor(bests[rt][reg], off, 16);
        const int oi = __shfl_xor(besti[rt][reg], off, 16);
        if (os > bests[rt][reg] || (os == bests[rt][reg] && oi < besti[rt][reg])) {
          bests[rt][reg] = os; besti[rt][reg] = oi;
        }
      }
    }
  }
  if (m == 0) {
#pragma unroll
    for (int rt = 0; rt < 2; ++rt)
#pragma unroll
      for (int reg = 0; reg < 4; ++reg) {
        const int row = wr0 + 16 * rt + 4 * q + reg;
        idx_g[R0 + row] = besti[rt][reg];  // plain store; hist kernel follows
      }
  }

  // ---- z_q (straight-through) + per-wave e_latent partial.
  // Shuffle broadcast: after the width-16 butterfly ALL lanes in a 16-group
  // hold that group's argmin for (rt, reg). Row 16rt+m -> group m>>2, reg m&3.
  const int sl = ((m >> 2) << 4) | m;  // any lane of group m>>2
  half8 zq[2][2];
  float es = 0.f;
#pragma unroll
  for (int rt = 0; rt < 2; ++rt) {
    const int b0 = __shfl(besti[rt][0], sl);
    const int b1 = __shfl(besti[rt][1], sl);
    const int b2 = __shfl(besti[rt][2], sl);
    const int b3 = __shfl(besti[rt][3], sl);
    const int r2 = m & 3;
    const int bi = (r2 == 0) ? b0 : (r2 == 1) ? b1 : (r2 == 2) ? b2 : b3;
#pragma unroll
    for (int ks2 = 0; ks2 < 2; ++ks2) {
      const float* cp = cb + (size_t)bi * 64 + ks2 * 32 + q * 8;
      const float4 c0 = *(const float4*)cp;
      const float4 c1 = *(const float4*)(cp + 4);
      float cv[8] = {c0.x, c0.y, c0.z, c0.w, c1.x, c1.y, c1.z, c1.w};
#pragma unroll
      for (int j = 0; j < 8; ++j) {
        const float z = (float)zfm[rt][ks2][j] + (float)zfr[rt][ks2][j];
        const float d = cv[j] - z;
        es = fmaf(d, d, es);
        zq[rt][ks2][j] = (_Float16)(z + d);
      }
    }
  }
#pragma unroll
  for (int off = 1; off < 64; off <<= 1) es += __shfl_xor(es, off, 64);
  if (lane == 0) esp_g[blockIdx.x * 4 + w] = es;  // no atomic

  // ---- Stage E prologue: issue chunk-0 WD2 loads (hide under stage D)
  const int nE = t >> 2, jE = t & 3;
  const char* srcE = wsb + D2P_O + (size_t)nE * 256 + jE * 64;
  _Float16* dstE = LP + nE * 136 + jE * 32;
  half8 stgE[4];
#pragma unroll
  for (int j = 0; j < 4; ++j) stgE[j] = *(const half8*)(srcE + j * 16);

  // ================= Stage D: dec1 (plain fp16, B direct)
  floatx4 accH[8][2];
#pragma unroll
  for (int nt = 0; nt < 8; ++nt)
#pragma unroll
    for (int rt = 0; rt < 2; ++rt) accH[nt][rt] = (floatx4){0.f, 0.f, 0.f, 0.f};
#pragma unroll
  for (int nt = 0; nt < 8; ++nt) {
#pragma unroll
    for (int ks2 = 0; ks2 < 2; ++ks2) {
      const half8 b = *(const half8*)(wsb + D1P_O + (size_t)(nt * 16 + m) * 128 + ks2 * 64 + q * 16);
#pragma unroll
      for (int rt = 0; rt < 2; ++rt) accH[nt][rt] = MFMA16(zq[rt][ks2], b, accH[nt][rt]);
    }
  }
  half8 h3f[2][4];
  for (int ks = 0; ks < 4; ++ks) {
#pragma unroll
    for (int h = 0; h < 2; ++h) {
      const int nt = 2 * ks + h;
      const float bias = db1[nt * 16 + m];
#pragma unroll
      for (int rt = 0; rt < 2; ++rt)
#pragma unroll
        for (int reg = 0; reg < 4; ++reg) {
          const float v = fmaxf(accH[nt][rt][reg] + bias, 0.f);
          WPS[(16 * rt + 4 * q + reg) * 40 + h * 16 + m] = (_Float16)v;
        }
    }
    LDS_FENCE();
#pragma unroll
    for (int rt = 0; rt < 2; ++rt)
      h3f[rt][ks] = *(const half8*)(WPS + (16 * rt + m) * 40 + q * 8);
  }

  // ================= Stage E: dec2 (staged WD2, T14 pipeline) fused w/ dec3
  floatx4 accO[2] = {(floatx4){0.f, 0.f, 0.f, 0.f}, (floatx4){0.f, 0.f, 0.f, 0.f}};
  for (int jc = 0; jc < 4; ++jc) {
    VMCNT0();
#pragma unroll
    for (int j = 0; j < 4; ++j) *(half8*)(dstE + j * 8) = stgE[j];
    LDS_FENCE();
    if (jc < 3) {
#pragma unroll
      for (int j = 0; j < 4; ++j)
        stgE[j] = *(const half8*)(srcE + (size_t)(jc + 1) * 16384 + j * 16);
    }
    BARRIER();

    floatx4 accD2[4][2];
#pragma unroll
    for (int nt = 0; nt < 4; ++nt)
#pragma unroll
      for (int rt = 0; rt < 2; ++rt) accD2[nt][rt] = (floatx4){0.f, 0.f, 0.f, 0.f};
#pragma unroll
    for (int nt = 0; nt < 4; ++nt) {
#pragma unroll
      for (int ks = 0; ks < 4; ++ks) {
        const half8 b = *(const half8*)(LP + (nt * 16 + m) * 136 + ks * 32 + q * 8);
#pragma unroll
        for (int rt = 0; rt < 2; ++rt) accD2[nt][rt] = MFMA16(h3f[rt][ks], b, accD2[nt][rt]);
      }
    }
    half8 b3[2];
#pragma unroll
    for (int ks2 = 0; ks2 < 2; ++ks2)
      b3[ks2] = *(const half8*)(wsb + D3P_O + (size_t)m * 512 + jc * 128 + ks2 * 64 + q * 16);
#pragma unroll
    for (int rt = 0; rt < 2; ++rt) {
#pragma unroll
      for (int nt = 0; nt < 4; ++nt) {
        const float bias = db2[jc * 64 + nt * 16 + m];
#pragma unroll
        for (int reg = 0; reg < 4; ++reg) {
          const float v = fmaxf(accD2[nt][rt][reg] + bias, 0.f);
          WPS[(4 * q + reg) * 72 + nt * 16 + m] = (_Float16)v;
        }
      }
      LDS_FENCE();
#pragma unroll
      for (int ks2 = 0; ks2 < 2; ++ks2) {
        const half8 am = *(const half8*)(WPS + m * 72 + ks2 * 32 + q * 8);
        accO[rt] = MFMA16(am, b3[ks2], accO[rt]);
      }
    }
    BARRIER();
  }
  if (m < 9) {
    const float bias = db3[m];
#pragma unroll
    for (int rt = 0; rt < 2; ++rt)
#pragma unroll
      for (int reg = 0; reg < 4; ++reg) {
        const size_t r = (size_t)(R0 + wr0 + 16 * rt + 4 * q + reg);
        out[r * 9 + m] = accO[rt][reg] + bias;
      }
  }
}

// =====================================================================
// Fused hist + finalize: 64 blocks. Each block LDS-histograms its 4096
// indices, atomicAdds nonzero bins into the global hist (<=1024 device
// atomics/block, 64 adds/address), then a no-spin ticket elects the last
// block to compute entropy + es sum + outputs.
__global__ __launch_bounds__(256) void hist_fin_kernel(
    const int* __restrict__ idx_g, const float* __restrict__ esp,
    int* __restrict__ gh, int* __restrict__ cnt, float* __restrict__ out2) {
  __shared__ int lh[1024];
  __shared__ double redd[256];
  __shared__ float rede[256];
  __shared__ int is_last;
  const int t = threadIdx.x;
#pragma unroll
  for (int i = 0; i < 4; ++i) lh[t * 4 + i] = 0;
  __syncthreads();
  for (int i = t; i < 4096; i += 256)
    atomicAdd(&lh[idx_g[blockIdx.x * 4096 + i]], 1);  // LDS atomic only
  __syncthreads();
#pragma unroll
  for (int i = 0; i < 4; ++i) {
    const int v = lh[t * 4 + i];
    if (v) atomicAdd(&gh[t * 4 + i], v);  // device-scope, 64 adds/address
  }
  __threadfence();
  if (t == 0) is_last = (atomicAdd(cnt, 1) == 63);
  __syncthreads();
  if (!is_last) return;

  // ---- last block: finalize
  double e = 0.0;
#pragma unroll
  for (int i = 0; i < 4; ++i) {
    const int h = atomicAdd(&gh[t * 4 + i], 0);  // coherent read
    const float pr = (float)h * (1.0f / (float)kN);
    e += (double)(pr * logf(pr + 1e-10f));
  }
  float es = 0.f;
#pragma unroll 8
  for (int k = 0; k < 32; ++k) es += esp[k * 256 + t];
  redd[t] = e;
  rede[t] = es;
  __syncthreads();
  for (int s = 128; s > 0; s >>= 1) {
    if (t < s) { redd[t] += redd[t + s]; rede[t] += rede[t + s]; }
    __syncthreads();
  }
  if (t == 0) {
    out2[0] = 1.25f * (rede[0] * (1.0f / ((float)kN * 64.0f)));
    out2[1] = expf((float)(-redd[0]));
  }
}

}  // namespace

extern "C" void kernel_launch(void* const* d_in, const int* in_sizes, int n_in,
                              void* d_out, int out_size, void* d_ws, size_t ws_size,
                              hipStream_t stream) {
  const float* x   = (const float*)d_in[0];
  const float* ew1 = (const float*)d_in[1];
  const float* eb1 = (const float*)d_in[2];
  const float* ew2 = (const float*)d_in[3];
  const float* eb2 = (const float*)d_in[4];
  const float* ew3 = (const float*)d_in[5];
  const float* eb3 = (const float*)d_in[6];
  const float* dw1 = (const float*)d_in[7];
  const float* db1 = (const float*)d_in[8];
  const float* dw2 = (const float*)d_in[9];
  const float* db2 = (const float*)d_in[10];
  const float* dw3 = (const float*)d_in[11];
  const float* db3 = (const float*)d_in[12];
  const float* cb  = (const float*)d_in[13];
  float* out = (float*)d_out;
  char* wsb = (char*)d_ws;

  int* idx_g = (int*)(wsb + IDX_O);
  float* esp = (float*)(wsb + ESP_O);
  int* gh = (int*)(wsb + GH_O);
  int* cnt = (int*)(wsb + CNT_O);

  prep_kernel<<<128, 256, 0, stream>>>(ew1, ew2, ew3, cb, dw1, dw2, dw3, wsb);
  vqvae_mega<<<kN / 128, 256, 0, stream>>>(x, eb1, eb2, eb3, db1, db2, db3, cb,
                                           wsb, out, idx_g, esp);
  hist_fin_kernel<<<64, 256, 0, stream>>>(idx_g, esp, gh, cnt,
                                          out + (size_t)kN * 9);
}